// Round 3
// baseline (211.686 us; speedup 1.0000x reference)
//
#include <hip/hip_runtime.h>

// Loss = sum over 4 Haar subbands of mean(|dwt(pred)-dwt(target)|) on
// [32,3,512,512] fp32. DWT linear -> e = pred - target. Per 2x2 block
// (a b / c d): |a+b+c+d|+|a+b-c-d|+|a-b+c-d|+|a-b-c+d|. Using
// |x+y|+|x-y| = 2*max(|x|,|y|) the block cost is
// 2*(max(|a+b|,|c+d|) + max(|a-b|,|c-d|)); the 2 and the 0.5 DWT norm
// cancel -> final scale 1/(32*3*256*256).
//
// R2 lesson: VGPR=32 showed the compiler serialized the loads (4 in
// flight, vmcnt(0) each round) -> latency-bound at 17% HBM. This round:
// 24 float4 loads hoisted per batch (24 KB in flight/wave), single
// occupancy generation (1024 blocks, 16 waves/CU at VGPR<=128).

#define IMG_W       512
#define NUM_BLOCKS  1024
#define BLOCK_SIZE  256
#define NTHREADS    (NUM_BLOCKS * BLOCK_SIZE)   // 262,144
#define TOTAL_WORK  (32 * 3 * 256 * 128)        // rowpairs * float4-cols = 3,145,728
#define ITEMS       (TOTAL_WORK / NTHREADS)     // 12 per thread
#define BATCH       6                           // loads hoisted per batch
#define N_SUB       6291456.0f

__global__ __launch_bounds__(BLOCK_SIZE, 4) void dwt_partial_kernel(
    const float* __restrict__ pred,
    const float* __restrict__ target,
    float* __restrict__ partials)
{
    const int tid = blockIdx.x * BLOCK_SIZE + threadIdx.x;
    float acc = 0.0f;

    #pragma unroll
    for (int h = 0; h < ITEMS / BATCH; ++h) {
        float4 pe[BATCH], po[BATCH], te[BATCH], to[BATCH];
        #pragma unroll
        for (int i = 0; i < BATCH; ++i) {
            const int t    = tid + (h * BATCH + i) * NTHREADS;
            const int rp   = t >> 7;        // rowpair index
            const int j    = t & 127;       // float4 column
            const int base = rp * (2 * IMG_W) + (j << 2);
            pe[i] = *(const float4*)(pred   + base);
            po[i] = *(const float4*)(pred   + base + IMG_W);
            te[i] = *(const float4*)(target + base);
            to[i] = *(const float4*)(target + base + IMG_W);
        }
        #pragma unroll
        for (int i = 0; i < BATCH; ++i) {
            const float a0 = pe[i].x - te[i].x, b0 = pe[i].y - te[i].y;
            const float c0 = po[i].x - to[i].x, d0 = po[i].y - to[i].y;
            const float a1 = pe[i].z - te[i].z, b1 = pe[i].w - te[i].w;
            const float c1 = po[i].z - to[i].z, d1 = po[i].w - to[i].w;

            const float s0 = a0 + b0, u0 = c0 + d0, r0 = a0 - b0, v0 = c0 - d0;
            const float s1 = a1 + b1, u1 = c1 + d1, r1 = a1 - b1, v1 = c1 - d1;

            acc += fmaxf(fabsf(s0), fabsf(u0)) + fmaxf(fabsf(r0), fabsf(v0));
            acc += fmaxf(fabsf(s1), fabsf(u1)) + fmaxf(fabsf(r1), fabsf(v1));
        }
    }

    // 64-lane shuffle reduction
    #pragma unroll
    for (int off = 32; off > 0; off >>= 1)
        acc += __shfl_down(acc, off, 64);

    __shared__ float wave_sums[BLOCK_SIZE / 64];
    const int lane = threadIdx.x & 63;
    const int wid  = threadIdx.x >> 6;
    if (lane == 0) wave_sums[wid] = acc;
    __syncthreads();

    if (threadIdx.x == 0)
        partials[blockIdx.x] = wave_sums[0] + wave_sums[1]
                             + wave_sums[2] + wave_sums[3];
}

__global__ __launch_bounds__(BLOCK_SIZE) void dwt_final_kernel(
    const float* __restrict__ partials,
    float* __restrict__ out)
{
    float acc = 0.0f;
    #pragma unroll
    for (int k = 0; k < NUM_BLOCKS / BLOCK_SIZE; ++k)
        acc += partials[threadIdx.x + k * BLOCK_SIZE];

    #pragma unroll
    for (int off = 32; off > 0; off >>= 1)
        acc += __shfl_down(acc, off, 64);

    __shared__ float wave_sums[BLOCK_SIZE / 64];
    const int lane = threadIdx.x & 63;
    const int wid  = threadIdx.x >> 6;
    if (lane == 0) wave_sums[wid] = acc;
    __syncthreads();

    if (threadIdx.x == 0)
        out[0] = (wave_sums[0] + wave_sums[1] + wave_sums[2] + wave_sums[3])
               * (1.0f / N_SUB);   // 2x from max-identity cancels the 0.5 DWT norm
}

extern "C" void kernel_launch(void* const* d_in, const int* in_sizes, int n_in,
                              void* d_out, int out_size, void* d_ws, size_t ws_size,
                              hipStream_t stream)
{
    const float* pred   = (const float*)d_in[0];
    const float* target = (const float*)d_in[1];
    float* partials     = (float*)d_ws;    // 1024 floats = 4 KB
    float* out          = (float*)d_out;

    dwt_partial_kernel<<<NUM_BLOCKS, BLOCK_SIZE, 0, stream>>>(pred, target, partials);
    dwt_final_kernel<<<1, BLOCK_SIZE, 0, stream>>>(partials, out);
}

// Round 5
// 193.056 us; speedup vs baseline: 1.0965x; 1.0965x over previous
//
#include <hip/hip_runtime.h>

// Loss = sum over 4 Haar subbands of mean(|dwt(pred)-dwt(target)|) on
// [32,3,512,512] fp32. DWT linear -> e = pred - target. Per 2x2 block
// (a b / c d), using |x+y|+|x-y| = 2*max(|x|,|y|):
//   contribution = 2*(max(|a+b|,|c+d|) + max(|a-b|,|c-d|))
// The 2 cancels the 0.5 DWT norm -> final scale 1/(32*3*256*256).
//
// R1-R3 lesson: kernel pinned at ~75us (2.7 TB/s delivered) whether data
// comes from HBM or L3; invariant to atomics/MLP/occupancy. Theory: stream
// locality — flat grid-stride teleports each block's address front 24MB per
// iteration, and pred/target are exactly 96MiB apart (channel aliasing).
// This round: contiguous 32KiB slab per block, linear sweep, pred-burst
// then target-burst, nontemporal loads (via raw ext_vector_type — the
// builtin rejects HIP_vector_type structs, R4 compile fail).

#define IMG_W        512
#define ROWPAIRS     (32 * 3 * 256)            // 24,576
#define NUM_BLOCKS   3072
#define BLOCK_SIZE   256
#define RP_PER_BLK   (ROWPAIRS / NUM_BLOCKS)   // 8 rowpairs = 32 KiB per tensor
#define N_SUB        6291456.0f

typedef float vfloat4 __attribute__((ext_vector_type(4)));

__device__ __forceinline__ vfloat4 nt_load4(const float* p) {
    return __builtin_nontemporal_load((const vfloat4*)p);
}

__global__ __launch_bounds__(BLOCK_SIZE) void dwt_partial_kernel(
    const float* __restrict__ pred,
    const float* __restrict__ target,
    float* __restrict__ partials)
{
    // Block owns rowpairs [rp0, rp0+8). Iteration covers 2 rowpairs
    // (256 threads = 2 rowpairs x 128 float4-cols).
    const int rp0  = blockIdx.x * RP_PER_BLK;
    const int rsel = threadIdx.x >> 7;         // which rowpair of the pair
    const int j    = threadIdx.x & 127;        // float4 column
    const int off0 = (rp0 + rsel) * (2 * IMG_W) + (j << 2);

    float acc = 0.0f;

    #pragma unroll
    for (int kk = 0; kk < RP_PER_BLK / 4; ++kk) {     // 2 outer iters
        const int o0 = off0 + (4 * kk)     * (2 * IMG_W);
        const int o1 = off0 + (4 * kk + 2) * (2 * IMG_W);

        // ---- pred burst (block-wide contiguous 16 KB) ----
        const vfloat4 pe0 = nt_load4(pred + o0);
        const vfloat4 po0 = nt_load4(pred + o0 + IMG_W);
        const vfloat4 pe1 = nt_load4(pred + o1);
        const vfloat4 po1 = nt_load4(pred + o1 + IMG_W);
        // ---- target burst ----
        const vfloat4 te0 = nt_load4(target + o0);
        const vfloat4 to0 = nt_load4(target + o0 + IMG_W);
        const vfloat4 te1 = nt_load4(target + o1);
        const vfloat4 to1 = nt_load4(target + o1 + IMG_W);

        {
            const float a0 = pe0.x - te0.x, b0 = pe0.y - te0.y;
            const float c0 = po0.x - to0.x, d0 = po0.y - to0.y;
            const float a1 = pe0.z - te0.z, b1 = pe0.w - te0.w;
            const float c1 = po0.z - to0.z, d1 = po0.w - to0.w;
            acc += fmaxf(fabsf(a0 + b0), fabsf(c0 + d0))
                 + fmaxf(fabsf(a0 - b0), fabsf(c0 - d0));
            acc += fmaxf(fabsf(a1 + b1), fabsf(c1 + d1))
                 + fmaxf(fabsf(a1 - b1), fabsf(c1 - d1));
        }
        {
            const float a0 = pe1.x - te1.x, b0 = pe1.y - te1.y;
            const float c0 = po1.x - to1.x, d0 = po1.y - to1.y;
            const float a1 = pe1.z - te1.z, b1 = pe1.w - te1.w;
            const float c1 = po1.z - to1.z, d1 = po1.w - to1.w;
            acc += fmaxf(fabsf(a0 + b0), fabsf(c0 + d0))
                 + fmaxf(fabsf(a0 - b0), fabsf(c0 - d0));
            acc += fmaxf(fabsf(a1 + b1), fabsf(c1 + d1))
                 + fmaxf(fabsf(a1 - b1), fabsf(c1 - d1));
        }
    }

    // 64-lane shuffle reduction
    #pragma unroll
    for (int off = 32; off > 0; off >>= 1)
        acc += __shfl_down(acc, off, 64);

    __shared__ float wave_sums[BLOCK_SIZE / 64];
    const int lane = threadIdx.x & 63;
    const int wid  = threadIdx.x >> 6;
    if (lane == 0) wave_sums[wid] = acc;
    __syncthreads();

    if (threadIdx.x == 0)
        partials[blockIdx.x] = wave_sums[0] + wave_sums[1]
                             + wave_sums[2] + wave_sums[3];
}

__global__ __launch_bounds__(BLOCK_SIZE) void dwt_final_kernel(
    const float* __restrict__ partials,
    float* __restrict__ out)
{
    float acc = 0.0f;
    #pragma unroll
    for (int k = 0; k < NUM_BLOCKS / BLOCK_SIZE; ++k)
        acc += partials[threadIdx.x + k * BLOCK_SIZE];

    #pragma unroll
    for (int off = 32; off > 0; off >>= 1)
        acc += __shfl_down(acc, off, 64);

    __shared__ float wave_sums[BLOCK_SIZE / 64];
    const int lane = threadIdx.x & 63;
    const int wid  = threadIdx.x >> 6;
    if (lane == 0) wave_sums[wid] = acc;
    __syncthreads();

    if (threadIdx.x == 0)
        out[0] = (wave_sums[0] + wave_sums[1] + wave_sums[2] + wave_sums[3])
               * (1.0f / N_SUB);
}

extern "C" void kernel_launch(void* const* d_in, const int* in_sizes, int n_in,
                              void* d_out, int out_size, void* d_ws, size_t ws_size,
                              hipStream_t stream)
{
    const float* pred   = (const float*)d_in[0];
    const float* target = (const float*)d_in[1];
    float* partials     = (float*)d_ws;    // 3072 floats = 12 KB
    float* out          = (float*)d_out;

    dwt_partial_kernel<<<NUM_BLOCKS, BLOCK_SIZE, 0, stream>>>(pred, target, partials);
    dwt_final_kernel<<<1, BLOCK_SIZE, 0, stream>>>(partials, out);
}